// Round 14
// baseline (24.868 us; speedup 1.0000x reference)
//
#include <hip/hip_runtime.h>

// S=8192, H=2048
// v = W^T h;  energies[s] = enc[s,:].v  (+b.h softmax-invariant, dropped)
// out = softmax(energies)
// 3 dispatches. Ledger: all fusion loses (R2,R7,R8,R11,R12); launch gap <1us (R12);
// intra-k2 micro-variants +-0.3us (R5..R13). This round: kv shuffle-reduce
// (kills 7 of 8 barriers) + k2 2-rows/wave with 16 NT loads in flight.
// ws floats: v[2048] | e[8192]

#define Hdim 2048
#define Sdim 8192

typedef float vfloat4 __attribute__((ext_vector_type(4)));

__global__ void kv_matvec(const float* __restrict__ W, const float* __restrict__ hid,
                          float* __restrict__ v) {
    // 256 blocks x 512 thr. Block owns 8 cols (XCD-contiguous), all 2048 rows.
    // Reduce: 5-step shfl_xor butterfly within wave (rl = t>>1), then 1 LDS tail.
    int b = blockIdx.x;
    int c0 = (b & 7) * 256 + (b >> 3) * 8;
    int t = threadIdx.x;
    int lane = t & 63, wv = t >> 6;          // 8 waves
    int cp = (t & 1) * 4;
    int rl = t >> 1;                          // 0..255
    float4 acc = {0.f, 0.f, 0.f, 0.f};
#pragma unroll
    for (int i = 0; i < 8; ++i) {
        int k = rl + 256 * i;
        float hk = hid[k];
        float4 w = *reinterpret_cast<const float4*>(W + (size_t)k * Hdim + c0 + cp);
        acc.x += w.x * hk;
        acc.y += w.y * hk;
        acc.z += w.z * hk;
        acc.w += w.w * hk;
    }
    // butterfly over lane bits 1..5 (rl within wave); lanes 0/1 end with wave sums
#pragma unroll
    for (int off = 2; off <= 32; off <<= 1) {
        acc.x += __shfl_xor(acc.x, off, 64);
        acc.y += __shfl_xor(acc.y, off, 64);
        acc.z += __shfl_xor(acc.z, off, 64);
        acc.w += __shfl_xor(acc.w, off, 64);
    }
    __shared__ float4 wsum[8][2];
    if (lane < 2) wsum[wv][lane] = acc;
    __syncthreads();
    if (t < 2) {
        float4 s = wsum[0][t];
#pragma unroll
        for (int w = 1; w < 8; ++w) {
            float4 o = wsum[w][t];
            s.x += o.x; s.y += o.y; s.z += o.z; s.w += o.w;
        }
        *reinterpret_cast<float4*>(v + c0 + t * 4) = s;
    }
}

__global__ __launch_bounds__(256) void k2_energies(
    const float* __restrict__ enc, const float* __restrict__ v, float* __restrict__ e) {
    // 1024 blocks x 256 thr; 4 waves/block, TWO rows per wave.
    // 16 NT loads issued before any use -> 2x load-issue duty cycle vs R13.
    __shared__ float v_lds[Hdim];
    int t = threadIdx.x;
    int lane = t & 63;
    size_t r0 = (size_t)blockIdx.x * 8 + (t >> 6) * 2;
    const float* pA = enc + r0 * Hdim;
    const float* pB = pA + Hdim;
    vfloat4 a[8], bb[8];
#pragma unroll
    for (int i = 0; i < 8; ++i)
        a[i] = __builtin_nontemporal_load(
            reinterpret_cast<const vfloat4*>(pA + i * 256 + lane * 4));
#pragma unroll
    for (int i = 0; i < 8; ++i)
        bb[i] = __builtin_nontemporal_load(
            reinterpret_cast<const vfloat4*>(pB + i * 256 + lane * 4));
    {
        float4* dst = reinterpret_cast<float4*>(v_lds);
        const float4* src = reinterpret_cast<const float4*>(v);
        dst[t] = src[t];
        dst[t + 256] = src[t + 256];
    }
    __syncthreads();
    float accA = 0.f, accB = 0.f;
#pragma unroll
    for (int i = 0; i < 8; ++i) {
        float4 w = *reinterpret_cast<float4*>(&v_lds[i * 256 + lane * 4]);
        accA += a[i].x * w.x + a[i].y * w.y + a[i].z * w.z + a[i].w * w.w;
        accB += bb[i].x * w.x + bb[i].y * w.y + bb[i].z * w.z + bb[i].w * w.w;
    }
#pragma unroll
    for (int off = 32; off > 0; off >>= 1) {
        accA += __shfl_xor(accA, off, 64);
        accB += __shfl_xor(accB, off, 64);
    }
    if (lane == 0) {
        e[r0] = accA;
        e[r0 + 1] = accB;
    }
}

__global__ void k3_par(const float* __restrict__ e, float* __restrict__ out) {
    // 32 blocks x 256 thr; each block redundantly reduces all 8192 energies
    // (identical order -> bitwise-identical M,L), then normalizes its 256 slice.
    __shared__ float red[4];
    __shared__ float bM, bL;
    int t = threadIdx.x, lane = t & 63, wv = t >> 6;
    float4 x[8];
#pragma unroll
    for (int i = 0; i < 8; ++i)
        x[i] = *reinterpret_cast<const float4*>(e + i * 1024 + t * 4);
    float m = x[0].x;
#pragma unroll
    for (int i = 0; i < 8; ++i) {
        m = fmaxf(m, fmaxf(fmaxf(x[i].x, x[i].y), fmaxf(x[i].z, x[i].w)));
    }
#pragma unroll
    for (int off = 32; off > 0; off >>= 1) m = fmaxf(m, __shfl_xor(m, off, 64));
    if (lane == 0) red[wv] = m;
    __syncthreads();
    if (t == 0) bM = fmaxf(fmaxf(red[0], red[1]), fmaxf(red[2], red[3]));
    __syncthreads();
    float M = bM;
    float l = 0.f;
#pragma unroll
    for (int i = 0; i < 8; ++i) {
        l += __expf(x[i].x - M) + __expf(x[i].y - M) +
             __expf(x[i].z - M) + __expf(x[i].w - M);
    }
#pragma unroll
    for (int off = 32; off > 0; off >>= 1) l += __shfl_xor(l, off, 64);
    __syncthreads();
    if (lane == 0) red[wv] = l;
    __syncthreads();
    if (t == 0) bL = red[0] + red[1] + red[2] + red[3];
    __syncthreads();
    float invL = 1.0f / bL;
    int idx = blockIdx.x * 256 + t;
    out[idx] = __expf(e[idx] - M) * invL;
}

extern "C" void kernel_launch(void* const* d_in, const int* in_sizes, int n_in,
                              void* d_out, int out_size, void* d_ws, size_t ws_size,
                              hipStream_t stream) {
    const float* hid = (const float*)d_in[0];   // (1, H)
    const float* enc = (const float*)d_in[1];   // (S, 1, H)
    const float* W   = (const float*)d_in[2];   // (H, H)
    // d_in[3] = b : dropped (softmax shift-invariant)
    float* out = (float*)d_out;                 // S floats
    float* ws = (float*)d_ws;

    float* v = ws;            // 2048
    float* e = v + Hdim;      // 8192

    kv_matvec<<<256, 512, 0, stream>>>(W, hid, v);
    k2_energies<<<Sdim / 8, 256, 0, stream>>>(enc, v, e);
    k3_par<<<32, 256, 0, stream>>>(e, out);
}